// Round 6
// baseline (2128.532 us; speedup 1.0000x reference)
//
#include <hip/hip_runtime.h>

#define NN 100000
#define NE 1600000
#define NB2 782         // (NN + 127) >> 7 buckets of 128 dst nodes
#define CAP2 2560       // bucket capacity (mean 2048, ~11 sigma headroom)
#define EPB 4096        // edges per block in bucket pass
#define BN_EPS 1e-5f

typedef _Float16 f16;
typedef _Float16 f16x2 __attribute__((ext_vector_type(2)));
typedef _Float16 f16x4 __attribute__((ext_vector_type(4)));
typedef _Float16 f16x8 __attribute__((ext_vector_type(8)));
typedef float f32x4v __attribute__((ext_vector_type(4)));

// ---------------- kInit: cursors + fp16 transposed weights ----------------
__global__ __launch_bounds__(256) void kInit(const float* __restrict__ W1,
                                             const float* __restrict__ W2,
                                             f16* __restrict__ W1t,
                                             f16* __restrict__ W2t,
                                             int* __restrict__ curD,
                                             int* __restrict__ curS) {
    int idx = blockIdx.x * 256 + threadIdx.x;
    if (idx < NB2) { curD[idx] = idx * CAP2; curS[idx] = idx * CAP2; }
    if (idx < 16384) {
        int n = idx >> 7, k = idx & 127;
        W1t[idx] = (f16)W1[k * 128 + n];
    } else if (idx < 24576) {
        int j = idx - 16384;
        int n = j >> 7, k = j & 127;
        W2t[j] = (f16)W2[k * 64 + n];
    }
}

// ---------------- kC: bucket edges by dst>>7 (pairs) and src>>7 (srcBuck) ----------------
__global__ __launch_bounds__(256) void kC(const int* __restrict__ src,
                                          const int* __restrict__ dst,
                                          int* __restrict__ curD,
                                          int* __restrict__ curS,
                                          unsigned* __restrict__ pairs,
                                          unsigned char* __restrict__ srcBuck) {
    __shared__ int hD[NB2], hS[NB2], bD_[NB2], bS_[NB2];
    for (int i = threadIdx.x; i < NB2; i += 256) { hD[i] = 0; hS[i] = 0; }
    __syncthreads();
    int e0 = blockIdx.x * EPB;
    int e1 = min(e0 + EPB, NE);
    // pass 1: count
    for (int e = e0 + threadIdx.x; e < e1; e += 256) {
        atomicAdd(&hD[dst[e] >> 7], 1);
        atomicAdd(&hS[src[e] >> 7], 1);
    }
    __syncthreads();
    // reserve global ranges, reset local cursors
    for (int i = threadIdx.x; i < NB2; i += 256) {
        bD_[i] = hD[i] ? atomicAdd(&curD[i], hD[i]) : 0;
        bS_[i] = hS[i] ? atomicAdd(&curS[i], hS[i]) : 0;
        hD[i] = 0; hS[i] = 0;
    }
    __syncthreads();
    // pass 2: place (packed records; defensive clamp vs capacity overflow)
    for (int e = e0 + threadIdx.x; e < e1; e += 256) {
        int d = dst[e], s = src[e];
        int db = d >> 7, sb = s >> 7;
        int rD = atomicAdd(&hD[db], 1);
        int posD = bD_[db] + rD;
        int limD = (db + 1) * CAP2 - 1;
        if (posD > limD) posD = limD;
        pairs[posD] = ((unsigned)s << 8) | (unsigned)(d & 127);
        int rS = atomicAdd(&hS[sb], 1);
        int posS = bS_[sb] + rS;
        int limS = (sb + 1) * CAP2 - 1;
        if (posS > limS) posS = limS;
        srcBuck[posS] = (unsigned char)(s & 127);
    }
}

// ---------------- kSortDeg: blocks [0,NB2): in-bucket counting sort by src>>9 + degI;
//                  blocks [NB2,2NB2): degO from srcBuck ----------------
__global__ __launch_bounds__(256) void kSortDeg(unsigned* __restrict__ pairs,
                                                const unsigned char* __restrict__ srcBuck,
                                                const int* __restrict__ curD,
                                                const int* __restrict__ curS,
                                                int* __restrict__ degI,
                                                int* __restrict__ degO) {
    int t = threadIdx.x;
    if (blockIdx.x < NB2) {
        __shared__ unsigned bufA[CAP2], bufB[CAP2];
        __shared__ int binC[256], binS[256], dcnt[128];
        int b = blockIdx.x;
        int p0 = b * CAP2;
        int n = min(curD[b] - p0, CAP2);
        binC[t] = 0;
        if (t < 128) dcnt[t] = 0;
        __syncthreads();
        for (int i = t; i < n; i += 256) {
            unsigned v = pairs[p0 + i];
            bufA[i] = v;
            atomicAdd(&binC[v >> 17], 1);   // band = src >> 9
            atomicAdd(&dcnt[v & 127u], 1);
        }
        __syncthreads();
        int c = binC[t];
        binS[t] = c;
        __syncthreads();
        for (int off = 1; off < 256; off <<= 1) {
            int x = (t >= off) ? binS[t - off] : 0;
            __syncthreads();
            binS[t] += x;
            __syncthreads();
        }
        binC[t] = binS[t] - c;   // exclusive start -> scatter cursor
        __syncthreads();
        for (int i = t; i < n; i += 256) {
            unsigned v = bufA[i];
            int pos = atomicAdd(&binC[v >> 17], 1);
            bufB[pos] = v;
        }
        __syncthreads();
        for (int i = t; i < n; i += 256) pairs[p0 + i] = bufB[i];
        int node = b * 128 + t;
        if (t < 128 && node < NN) degI[node] = dcnt[t];
    } else {
        __shared__ int cnt[128];
        int b = blockIdx.x - NB2;
        if (t < 128) cnt[t] = 0;
        __syncthreads();
        int p0 = b * CAP2;
        int p1 = min(curS[b], p0 + CAP2);
        for (int p = p0 + t; p < p1; p += 256)
            atomicAdd(&cnt[srcBuck[p]], 1);
        __syncthreads();
        int node = b * 128 + t;
        if (t < 128 && node < NN) degO[node] = cnt[t];
    }
}

// ---------------- GEMM1 (MFMA f16): x1h = (h .* rsqrt(degO)) @ W1 ----------------
__global__ __launch_bounds__(256) void k_gemm1(const float* __restrict__ h,
                                               const f16* __restrict__ W1t,
                                               const int* __restrict__ degO,
                                               f16* __restrict__ x1h) {
    __shared__ f16 Ah[128 * 128];
    __shared__ f16 Bt[128 * 128];
    int tid = threadIdx.x;
    int row0 = blockIdx.x * 128;
#pragma unroll
    for (int p = 0; p < 8; ++p) {
        int fi = p * 256 + tid;
        int r = fi >> 4, c = fi & 15;
        uint4 v = *(const uint4*)&W1t[fi * 8];
        *(uint4*)&Bt[r * 128 + ((c ^ (r & 7)) * 8)] = v;
    }
#pragma unroll
    for (int p = 0; p < 16; ++p) {
        int fi = p * 256 + tid;
        int r = fi >> 5, c4 = fi & 31;
        int grow = row0 + r;
        float4 av = float4{0.f, 0.f, 0.f, 0.f};
        float dv = 1.f;
        if (grow < NN) {
            av = *(const float4*)&h[(size_t)grow * 128 + c4 * 4];
            dv = (float)degO[grow];
        }
        float rs = rsqrtf(fmaxf(dv, 1.f));
        f16x4 t;
        t[0] = (f16)(av.x * rs); t[1] = (f16)(av.y * rs);
        t[2] = (f16)(av.z * rs); t[3] = (f16)(av.w * rs);
        int c8 = c4 >> 1, off = (c4 & 1) * 4;
        *(f16x4*)&Ah[r * 128 + ((c8 ^ (r & 7)) * 8) + off] = t;
    }
    __syncthreads();
    int l = tid & 63, w = tid >> 6;
    int lr = l & 15, g = l >> 4;
    int m0 = w * 32;
    f16x8 a[2][4];
#pragma unroll
    for (int m = 0; m < 2; ++m)
#pragma unroll
        for (int kk = 0; kk < 4; ++kk) {
            int row = m0 + m * 16 + lr;
            a[m][kk] = *(f16x8*)&Ah[row * 128 + (((kk * 4 + g) ^ (row & 7)) * 8)];
        }
    f32x4v acc[2][8];
#pragma unroll
    for (int m = 0; m < 2; ++m)
#pragma unroll
        for (int n = 0; n < 8; ++n) acc[m][n] = f32x4v{0.f, 0.f, 0.f, 0.f};
#pragma unroll
    for (int n = 0; n < 8; ++n) {
        int colr = n * 16 + lr;
        f16x8 b[4];
#pragma unroll
        for (int kk = 0; kk < 4; ++kk)
            b[kk] = *(f16x8*)&Bt[colr * 128 + (((kk * 4 + g) ^ (colr & 7)) * 8)];
#pragma unroll
        for (int m = 0; m < 2; ++m)
#pragma unroll
            for (int kk = 0; kk < 4; ++kk)
                acc[m][n] = __builtin_amdgcn_mfma_f32_16x16x32_f16(a[m][kk], b[kk], acc[m][n], 0, 0, 0);
    }
    __syncthreads();
#pragma unroll
    for (int m = 0; m < 2; ++m)
#pragma unroll
        for (int n = 0; n < 8; ++n)
#pragma unroll
            for (int q = 0; q < 4; ++q) {
                int row = m0 + m * 16 + g * 4 + q;
                Ah[row * 128 + n * 16 + lr] = (f16)acc[m][n][q];
            }
    __syncthreads();
#pragma unroll
    for (int p = 0; p < 8; ++p) {
        int idx = p * 64 + l;
        int r = idx >> 4, c = idx & 15;
        int row = m0 + r, grow = row0 + row;
        uint4 v = *(uint4*)&Ah[row * 128 + c * 8];
        if (grow < NN) *(uint4*)&x1h[(size_t)grow * 128 + c * 8] = v;
    }
}

// ---------------- gather1F: frontal edge-streamed aggregation, 128 feats ----------------
__global__ __launch_bounds__(512) void k_gather1F(const f16* __restrict__ x1h,
                                                  const unsigned* __restrict__ pairs,
                                                  const int* __restrict__ curD,
                                                  const int* __restrict__ degI,
                                                  const float* __restrict__ b1,
                                                  f16* __restrict__ y1h,
                                                  float* __restrict__ part) {
    __shared__ float acc[128 * 128];
    __shared__ float rs[128];
    int b = blockIdx.x;
    int tid = threadIdx.x;
    int p0 = b * CAP2;
    int n = min(curD[b] - p0, CAP2);
    for (int i = tid; i < 128 * 128; i += 512) acc[i] = 0.f;
    if (tid < 128) {
        int gn = b * 128 + tid;
        float d = (gn < NN) ? (float)degI[gn] : 1.f;
        rs[tid] = rsqrtf(fmaxf(d, 1.f));
    }
    __syncthreads();
    int w = tid >> 6, lane = tid & 63;
    for (int base = w * 8; base < n; base += 64) {
        int m = n - base; if (m > 8) m = 8;
        unsigned vv[8]; float2 xf[8];
#pragma unroll
        for (int u = 0; u < 8; ++u) {
            if (u < m) {
                unsigned v = pairs[p0 + base + u];
                vv[u] = v;
                unsigned rv = *(const unsigned*)&x1h[(size_t)(v >> 8) * 128 + lane * 2];
                f16x2 hv = __builtin_bit_cast(f16x2, rv);
                xf[u] = float2{(float)hv[0], (float)hv[1]};
            }
        }
#pragma unroll
        for (int u = 0; u < 8; ++u) {
            if (u < m) {
                int dl = vv[u] & 127;
                // feat-permuted slots: feat f -> (f>>1) + (f&1)*64  (stride-4B, conflict-free)
                atomicAdd(&acc[dl * 128 + lane], xf[u].x);
                atomicAdd(&acc[dl * 128 + 64 + lane], xf[u].y);
            }
        }
    }
    __syncthreads();
    // epilogue: y1h = fp16(acc * rs + b1); BN partial sums per channel
    int nd0 = tid >> 7, f = tid & 127;
    int slot = (f >> 1) + (f & 1) * 64;
    float s = 0.f, ss = 0.f;
    float bv = b1[f];
    for (int g = 0; g < 32; ++g) {
        int node = g * 4 + nd0;
        int gnode = b * 128 + node;
        if (gnode < NN) {
            float val = acc[node * 128 + slot] * rs[node] + bv;
            f16 vh = (f16)val;
            y1h[(size_t)gnode * 128 + f] = vh;
            float vf = (float)vh;
            s += vf; ss += vf * vf;
        }
    }
    __syncthreads();
    acc[tid] = s; acc[512 + tid] = ss;
    __syncthreads();
    if (tid < 128) {
        float ts = acc[tid] + acc[tid + 128] + acc[tid + 256] + acc[tid + 384];
        float tss = acc[512 + tid] + acc[512 + tid + 128] + acc[512 + tid + 256] + acc[512 + tid + 384];
        part[(size_t)b * 256 + tid] = ts;
        part[(size_t)b * 256 + 128 + tid] = tss;
    }
}

// ---------------- k_bnred: reduce per-block BN partials -> stats ----------------
__global__ __launch_bounds__(256) void k_bnred(const float* __restrict__ part,
                                               float* __restrict__ stats) {
    __shared__ float red[256];
    int j = blockIdx.x;      // 0..255 (j<128: sum_f, j>=128: sumsq_{j-128})
    int t = threadIdx.x;
    float s = 0.f;
    for (int b = t; b < NB2; b += 256) s += part[(size_t)b * 256 + j];
    red[t] = s;
    __syncthreads();
    for (int off = 128; off > 0; off >>= 1) {
        if (t < off) red[t] += red[t + off];
        __syncthreads();
    }
    if (t == 0) stats[j] = red[0];
}

__global__ __launch_bounds__(128) void k_bnfinal(float* __restrict__ stats,
                                                 const float* __restrict__ gamma,
                                                 const float* __restrict__ beta) {
    int f = threadIdx.x;
    float mean = stats[f] * (1.f / NN);
    float var = stats[128 + f] * (1.f / NN) - mean * mean;
    var = fmaxf(var, 0.f);
    float sc = gamma[f] * rsqrtf(var + BN_EPS);
    stats[256 + f] = sc;
    stats[384 + f] = beta[f] - mean * sc;
}

// ---------------- GEMM2 (MFMA f16): x2h = (relu(BN(y1)) .* rsqrt(degO)) @ W2 ----------------
__global__ __launch_bounds__(256) void k_gemm2(const f16* __restrict__ y1h,
                                               const f16* __restrict__ W2t,
                                               const int* __restrict__ degO,
                                               const float* __restrict__ stats,
                                               f16* __restrict__ x2h) {
    __shared__ f16 Ah[128 * 128];
    __shared__ f16 Bt[64 * 128];
    __shared__ float sc[128], sh[128];
    int tid = threadIdx.x;
    int row0 = blockIdx.x * 128;
    if (tid < 128) { sc[tid] = stats[256 + tid]; sh[tid] = stats[384 + tid]; }
#pragma unroll
    for (int p = 0; p < 4; ++p) {
        int fi = p * 256 + tid;
        int r = fi >> 4, c = fi & 15;
        uint4 v = *(const uint4*)&W2t[fi * 8];
        *(uint4*)&Bt[r * 128 + ((c ^ (r & 7)) * 8)] = v;
    }
    __syncthreads();
#pragma unroll
    for (int p = 0; p < 8; ++p) {
        int fi = p * 256 + tid;
        int r = fi >> 4, c = fi & 15;
        int grow = row0 + r;
        f16x8 t;
        if (grow < NN) {
            uint4 v = *(const uint4*)&y1h[(size_t)grow * 128 + c * 8];
            const f16* hp = (const f16*)&v;
            float rs = rsqrtf(fmaxf((float)degO[grow], 1.f));
#pragma unroll
            for (int i = 0; i < 8; ++i) {
                int ch = c * 8 + i;
                float x = (float)hp[i] * sc[ch] + sh[ch];
                t[i] = (f16)(fmaxf(x, 0.f) * rs);
            }
        } else {
#pragma unroll
            for (int i = 0; i < 8; ++i) t[i] = (f16)0.f;
        }
        *(f16x8*)&Ah[r * 128 + ((c ^ (r & 7)) * 8)] = t;
    }
    __syncthreads();
    int l = tid & 63, w = tid >> 6;
    int lr = l & 15, g = l >> 4;
    int m0 = w * 32;
    f16x8 a[2][4];
#pragma unroll
    for (int m = 0; m < 2; ++m)
#pragma unroll
        for (int kk = 0; kk < 4; ++kk) {
            int row = m0 + m * 16 + lr;
            a[m][kk] = *(f16x8*)&Ah[row * 128 + (((kk * 4 + g) ^ (row & 7)) * 8)];
        }
    f32x4v acc[2][4];
#pragma unroll
    for (int m = 0; m < 2; ++m)
#pragma unroll
        for (int n = 0; n < 4; ++n) acc[m][n] = f32x4v{0.f, 0.f, 0.f, 0.f};
#pragma unroll
    for (int n = 0; n < 4; ++n) {
        int colr = n * 16 + lr;
        f16x8 b[4];
#pragma unroll
        for (int kk = 0; kk < 4; ++kk)
            b[kk] = *(f16x8*)&Bt[colr * 128 + (((kk * 4 + g) ^ (colr & 7)) * 8)];
#pragma unroll
        for (int m = 0; m < 2; ++m)
#pragma unroll
            for (int kk = 0; kk < 4; ++kk)
                acc[m][n] = __builtin_amdgcn_mfma_f32_16x16x32_f16(a[m][kk], b[kk], acc[m][n], 0, 0, 0);
    }
    __syncthreads();
#pragma unroll
    for (int m = 0; m < 2; ++m)
#pragma unroll
        for (int n = 0; n < 4; ++n)
#pragma unroll
            for (int q = 0; q < 4; ++q) {
                int row = m0 + m * 16 + g * 4 + q;
                Ah[row * 64 + n * 16 + lr] = (f16)acc[m][n][q];
            }
    __syncthreads();
#pragma unroll
    for (int p = 0; p < 4; ++p) {
        int idx = p * 64 + l;
        int r = idx >> 3, c = idx & 7;
        int row = m0 + r, grow = row0 + row;
        uint4 v = *(uint4*)&Ah[row * 64 + c * 8];
        if (grow < NN) *(uint4*)&x2h[(size_t)grow * 64 + c * 8] = v;
    }
}

// ---------------- gather2F: frontal edge-streamed aggregation, 64 feats, fp32 out ----------------
__global__ __launch_bounds__(512) void k_gather2F(const f16* __restrict__ x2h,
                                                  const unsigned* __restrict__ pairs,
                                                  const int* __restrict__ curD,
                                                  const int* __restrict__ degI,
                                                  const float* __restrict__ b2,
                                                  float* __restrict__ out) {
    __shared__ float acc[128 * 64];
    __shared__ float rs[128];
    int b = blockIdx.x, tid = threadIdx.x;
    int p0 = b * CAP2;
    int n = min(curD[b] - p0, CAP2);
    for (int i = tid; i < 128 * 64; i += 512) acc[i] = 0.f;
    if (tid < 128) {
        int gn = b * 128 + tid;
        float d = (gn < NN) ? (float)degI[gn] : 1.f;
        rs[tid] = rsqrtf(fmaxf(d, 1.f));
    }
    __syncthreads();
    int half = tid >> 5;     // 0..15
    int hl = tid & 31;
    for (int base = half * 8; base < n; base += 128) {
        int m = n - base; if (m > 8) m = 8;
        unsigned vv[8]; float2 xf[8];
#pragma unroll
        for (int u = 0; u < 8; ++u) {
            if (u < m) {
                unsigned v = pairs[p0 + base + u];
                vv[u] = v;
                unsigned rv = *(const unsigned*)&x2h[(size_t)(v >> 8) * 64 + hl * 2];
                f16x2 hv = __builtin_bit_cast(f16x2, rv);
                xf[u] = float2{(float)hv[0], (float)hv[1]};
            }
        }
#pragma unroll
        for (int u = 0; u < 8; ++u) {
            if (u < m) {
                int dl = vv[u] & 127;
                atomicAdd(&acc[dl * 64 + hl], xf[u].x);
                atomicAdd(&acc[dl * 64 + 32 + hl], xf[u].y);
            }
        }
    }
    __syncthreads();
    int nd0 = tid >> 6, f = tid & 63;
    int slot = (f >> 1) + (f & 1) * 32;
    float bv = b2[f];
    for (int g = 0; g < 16; ++g) {
        int node = g * 8 + nd0;
        int gnode = b * 128 + node;
        if (gnode < NN)
            out[(size_t)gnode * 64 + f] = acc[node * 64 + slot] * rs[node] + bv;
    }
}

extern "C" void kernel_launch(void* const* d_in, const int* in_sizes, int n_in,
                              void* d_out, int out_size, void* d_ws, size_t ws_size,
                              hipStream_t stream) {
    const float* h     = (const float*)d_in[0];
    const float* W1    = (const float*)d_in[1];
    const float* b1    = (const float*)d_in[2];
    const float* W2    = (const float*)d_in[3];
    const float* b2    = (const float*)d_in[4];
    const float* gamma = (const float*)d_in[5];
    const float* beta  = (const float*)d_in[6];
    const int*   src   = (const int*)d_in[7];
    const int*   dst   = (const int*)d_in[8];
    float* out = (float*)d_out;

    const size_t BSZ2 = (size_t)NB2 * CAP2;   // 2,001,920 slots

    // workspace layout (int units from base)
    int* base = (int*)d_ws;
    int* curD = base;                         // NB2
    int* curS = curD + NB2;                   // NB2
    int* degI = curS + NB2;                   // NN
    int* degO = degI + NN;                    // NN
    float* stats = (float*)(degO + NN);       // 512
    float* part  = stats + 512;               // NB2*256
    unsigned* pairs = (unsigned*)(part + (size_t)NB2 * 256);   // BSZ2 u32
    unsigned char* srcBuck = (unsigned char*)(pairs + BSZ2);   // BSZ2 bytes
    size_t o = (size_t)(2 * NB2) + 2 * NN + 512 + (size_t)NB2 * 256 + BSZ2 + (BSZ2 + 3) / 4;
    o = (o + 3) & ~(size_t)3;                 // 16B align
    f16* W1t = (f16*)(base + o);              // 16384 halves
    f16* W2t = W1t + 16384;                   // 8192 halves
    o += 8192 + 4096;
    f16* x1h = (f16*)(base + o);              // NN*128 halves
    o += (size_t)NN * 64;
    f16* y1h = (f16*)(base + o);              // NN*128 halves
    f16* x2h = x1h;                           // reuse (x1h dead after gather1)

    kInit<<<97, 256, 0, stream>>>(W1, W2, W1t, W2t, curD, curS);

    int bgrid = (NE + EPB - 1) / EPB;         // 391
    kC<<<bgrid, 256, 0, stream>>>(src, dst, curD, curS, pairs, srcBuck);
    kSortDeg<<<2 * NB2, 256, 0, stream>>>(pairs, srcBuck, curD, curS, degI, degO);

    int ggrid = (NN + 127) / 128;             // 782
    k_gemm1<<<ggrid, 256, 0, stream>>>(h, W1t, degO, x1h);
    k_gather1F<<<NB2, 512, 0, stream>>>(x1h, pairs, curD, degI, b1, y1h, part);
    k_bnred<<<256, 256, 0, stream>>>(part, stats);
    k_bnfinal<<<1, 128, 0, stream>>>(stats, gamma, beta);
    k_gemm2<<<ggrid, 256, 0, stream>>>(y1h, W2t, degO, stats, x2h);
    k_gather2F<<<NB2, 512, 0, stream>>>(x2h, pairs, curD, degI, b2, out);
}

// Round 7
// 253.288 us; speedup vs baseline: 8.4036x; 8.4036x over previous
//
#include <hip/hip_runtime.h>

#define NN 100000
#define NE 1600000
#define NB 391          // (NN + 255) >> 8 buckets of 256 dst nodes
#define CAP 5120        // bucket capacity (mean 4092, ~16 sigma headroom)
#define EPB 4096        // edges per block in bucket pass
#define NG1 6250        // gather1 blocks = NN/16
#define BN_EPS 1e-5f

typedef _Float16 f16;
typedef _Float16 f16x4 __attribute__((ext_vector_type(4)));
typedef _Float16 f16x8 __attribute__((ext_vector_type(8)));
typedef float f32x4v __attribute__((ext_vector_type(4)));

// ---------------- kInit: cursors + stats zero + fp16 transposed weights ----------------
__global__ __launch_bounds__(256) void kInit(const float* __restrict__ W1,
                                             const float* __restrict__ W2,
                                             f16* __restrict__ W1t,
                                             f16* __restrict__ W2t,
                                             int* __restrict__ curD,
                                             int* __restrict__ curS,
                                             float* __restrict__ stats) {
    int idx = blockIdx.x * 256 + threadIdx.x;
    if (idx < NB) { curD[idx] = idx * CAP; curS[idx] = idx * CAP; }
    if (idx < 512) stats[idx] = 0.f;
    if (idx < 16384) {
        int n = idx >> 7, k = idx & 127;
        W1t[idx] = (f16)W1[k * 128 + n];
    } else if (idx < 24576) {
        int j = idx - 16384;
        int n = j >> 7, k = j & 127;
        W2t[j] = (f16)W2[k * 64 + n];
    }
}

// ---------------- kC: bucket edges by dst>>8 (pairs) and src>>8 (srcBuck), single global read ----------------
__global__ __launch_bounds__(256) void kC(const int* __restrict__ src,
                                          const int* __restrict__ dst,
                                          int* __restrict__ curD,
                                          int* __restrict__ curS,
                                          unsigned* __restrict__ pairs,
                                          unsigned char* __restrict__ srcBuck) {
    __shared__ int sA[EPB], dA[EPB];
    __shared__ int hD[NB], hS[NB], bD_[NB], bS_[NB];
    int t = threadIdx.x;
    for (int i = t; i < NB; i += 256) { hD[i] = 0; hS[i] = 0; }
    __syncthreads();
    int e0 = blockIdx.x * EPB;
    int ne = min(EPB, NE - e0);
    // single global read: cache edges in LDS, count buckets
    for (int i = t; i < ne; i += 256) {
        int s = src[e0 + i], d = dst[e0 + i];
        sA[i] = s; dA[i] = d;
        atomicAdd(&hD[d >> 8], 1);
        atomicAdd(&hS[s >> 8], 1);
    }
    __syncthreads();
    // reserve global ranges, reset local cursors
    for (int i = t; i < NB; i += 256) {
        bD_[i] = hD[i] ? atomicAdd(&curD[i], hD[i]) : 0;
        bS_[i] = hS[i] ? atomicAdd(&curS[i], hS[i]) : 0;
        hD[i] = 0; hS[i] = 0;
    }
    __syncthreads();
    // place from LDS (packed records; defensive clamp vs capacity overflow)
    for (int i = t; i < ne; i += 256) {
        int s = sA[i], d = dA[i];
        int db = d >> 8, sb = s >> 8;
        int rD = atomicAdd(&hD[db], 1);
        int posD = bD_[db] + rD;
        int limD = (db + 1) * CAP - 1;
        if (posD > limD) posD = limD;
        pairs[posD] = ((unsigned)s << 8) | (unsigned)(d & 255);
        int rS = atomicAdd(&hS[sb], 1);
        int posS = bS_[sb] + rS;
        int limS = (sb + 1) * CAP - 1;
        if (posS > limS) posS = limS;
        srcBuck[posS] = (unsigned char)(s & 255);
    }
}

// ---------------- kDE: blocks [0,NB): band-sorted per-bucket CSR; [NB,2NB): degO ----------------
__global__ __launch_bounds__(256) void kDE(const unsigned* __restrict__ pairs,
                                           const unsigned char* __restrict__ srcBuck,
                                           const int* __restrict__ curD,
                                           const int* __restrict__ curS,
                                           int* __restrict__ rowS,
                                           int* __restrict__ rowE,
                                           int* __restrict__ col,
                                           int* __restrict__ degO) {
    __shared__ unsigned bufA[CAP], bufB[CAP];     // 40 KB
    __shared__ int binC[256], binS[256];          // src-band hist/scan
    __shared__ int cnt[256], csc[256];            // node hist/scan
    int t = threadIdx.x;
    if (blockIdx.x < NB) {
        int b = blockIdx.x;
        int p0 = b * CAP;
        int n = min(curD[b] - p0, CAP);
        binC[t] = 0; cnt[t] = 0;
        __syncthreads();
        for (int i = t; i < n; i += 256) {
            unsigned v = pairs[p0 + i];
            bufA[i] = v;
            atomicAdd(&binC[v >> 17], 1);   // band = src >> 9  (< 196)
            atomicAdd(&cnt[v & 255u], 1);   // node within bucket
        }
        __syncthreads();
        int vB = binC[t], vN = cnt[t];
        binS[t] = vB; csc[t] = vN;
        __syncthreads();
        for (int off = 1; off < 256; off <<= 1) {
            int xB = (t >= off) ? binS[t - off] : 0;
            int xN = (t >= off) ? csc[t - off] : 0;
            __syncthreads();
            binS[t] += xB; csc[t] += xN;
            __syncthreads();
        }
        int node = b * 256 + t;
        int nodeStart = csc[t] - vN;
        if (node < NN) { rowS[node] = p0 + nodeStart; rowE[node] = p0 + nodeStart + vN; }
        binC[t] = binS[t] - vB;   // band scatter cursor
        cnt[t] = nodeStart;       // node scatter cursor
        __syncthreads();
        // sort by src-band into bufB
        for (int i = t; i < n; i += 256) {
            unsigned v = bufA[i];
            int pos = atomicAdd(&binC[v >> 17], 1);
            bufB[pos] = v;
        }
        __syncthreads();
        // scatter band-sorted records to col -> per-node lists ~ascending in src
        for (int i = t; i < n; i += 256) {
            unsigned v = bufB[i];
            int r = atomicAdd(&cnt[v & 255u], 1);
            col[p0 + r] = (int)(v >> 8);
        }
    } else {
        int b = blockIdx.x - NB;
        cnt[t] = 0;
        __syncthreads();
        int p0 = b * CAP;
        int p1 = min(curS[b], p0 + CAP);
        for (int p = p0 + t; p < p1; p += 256)
            atomicAdd(&cnt[srcBuck[p]], 1);
        __syncthreads();
        int node = b * 256 + t;
        if (node < NN) degO[node] = cnt[t];
    }
}

// ---------------- GEMM1 (MFMA f16): x1h = (h .* rsqrt(degO)) @ W1 ----------------
__global__ __launch_bounds__(256) void k_gemm1(const float* __restrict__ h,
                                               const f16* __restrict__ W1t,
                                               const int* __restrict__ degO,
                                               f16* __restrict__ x1h) {
    __shared__ f16 Ah[128 * 128];
    __shared__ f16 Bt[128 * 128];
    __shared__ float rsA[128];
    int tid = threadIdx.x;
    int row0 = blockIdx.x * 128;
    if (tid < 128) {
        int r = row0 + tid;
        float d = (r < NN) ? (float)degO[r] : 1.f;
        rsA[tid] = rsqrtf(fmaxf(d, 1.f));
    }
#pragma unroll
    for (int p = 0; p < 8; ++p) {
        int fi = p * 256 + tid;
        int r = fi >> 4, c = fi & 15;
        uint4 v = *(const uint4*)&W1t[fi * 8];
        *(uint4*)&Bt[r * 128 + ((c ^ (r & 7)) * 8)] = v;
    }
    __syncthreads();
#pragma unroll
    for (int p = 0; p < 16; ++p) {
        int fi = p * 256 + tid;
        int r = fi >> 5, c4 = fi & 31;
        int grow = row0 + r;
        float4 av = float4{0.f, 0.f, 0.f, 0.f};
        if (grow < NN) av = *(const float4*)&h[(size_t)grow * 128 + c4 * 4];
        float rs = rsA[r];
        f16x4 t;
        t[0] = (f16)(av.x * rs); t[1] = (f16)(av.y * rs);
        t[2] = (f16)(av.z * rs); t[3] = (f16)(av.w * rs);
        int c8 = c4 >> 1, off = (c4 & 1) * 4;
        *(f16x4*)&Ah[r * 128 + ((c8 ^ (r & 7)) * 8) + off] = t;
    }
    __syncthreads();
    int l = tid & 63, w = tid >> 6;
    int lr = l & 15, g = l >> 4;
    int m0 = w * 32;
    f16x8 a[2][4];
#pragma unroll
    for (int m = 0; m < 2; ++m)
#pragma unroll
        for (int kk = 0; kk < 4; ++kk) {
            int row = m0 + m * 16 + lr;
            a[m][kk] = *(f16x8*)&Ah[row * 128 + (((kk * 4 + g) ^ (row & 7)) * 8)];
        }
    f32x4v acc[2][8];
#pragma unroll
    for (int m = 0; m < 2; ++m)
#pragma unroll
        for (int n = 0; n < 8; ++n) acc[m][n] = f32x4v{0.f, 0.f, 0.f, 0.f};
#pragma unroll
    for (int n = 0; n < 8; ++n) {
        int colr = n * 16 + lr;
        f16x8 b[4];
#pragma unroll
        for (int kk = 0; kk < 4; ++kk)
            b[kk] = *(f16x8*)&Bt[colr * 128 + (((kk * 4 + g) ^ (colr & 7)) * 8)];
#pragma unroll
        for (int m = 0; m < 2; ++m)
#pragma unroll
            for (int kk = 0; kk < 4; ++kk)
                acc[m][n] = __builtin_amdgcn_mfma_f32_16x16x32_f16(a[m][kk], b[kk], acc[m][n], 0, 0, 0);
    }
    __syncthreads();
#pragma unroll
    for (int m = 0; m < 2; ++m)
#pragma unroll
        for (int n = 0; n < 8; ++n)
#pragma unroll
            for (int q = 0; q < 4; ++q) {
                int row = m0 + m * 16 + g * 4 + q;
                Ah[row * 128 + n * 16 + lr] = (f16)acc[m][n][q];
            }
    __syncthreads();
#pragma unroll
    for (int p = 0; p < 8; ++p) {
        int idx = p * 64 + l;
        int r = idx >> 4, c = idx & 15;
        int row = m0 + r, grow = row0 + row;
        uint4 v = *(uint4*)&Ah[row * 128 + c * 8];
        if (grow < NN) *(uint4*)&x1h[(size_t)grow * 128 + c * 8] = v;
    }
}

// ---------------- gather1: y1h = fp16( (sum_j x1h[col[j]]) * rsqrt(degI) + b1 ) + BN partials ----------------
__global__ __launch_bounds__(256) void k_gather1(const f16* __restrict__ x1h,
                                                 const int* __restrict__ rowS,
                                                 const int* __restrict__ rowE,
                                                 const int* __restrict__ col,
                                                 const float* __restrict__ b1,
                                                 f16* __restrict__ y1h,
                                                 float* __restrict__ part) {
    __shared__ float red[4 * 16 * 16];
    int tid = threadIdx.x;
    int bid = blockIdx.x;
    int node = bid * 16 + (tid >> 4);     // NN = 6250*16 exactly, no tail
    int f8 = tid & 15;
    int s0 = rowS[node], s1 = rowE[node];
    const uint4* x4 = (const uint4*)x1h;
    float acc[8] = {0.f, 0.f, 0.f, 0.f, 0.f, 0.f, 0.f, 0.f};
    int j = s0;
    for (; j + 3 < s1; j += 4) {
        int a0 = col[j], a1 = col[j + 1], a2 = col[j + 2], a3 = col[j + 3];
        uint4 v0 = x4[(size_t)a0 * 16 + f8];
        uint4 v1 = x4[(size_t)a1 * 16 + f8];
        uint4 v2 = x4[(size_t)a2 * 16 + f8];
        uint4 v3 = x4[(size_t)a3 * 16 + f8];
        const f16* h0 = (const f16*)&v0; const f16* h1 = (const f16*)&v1;
        const f16* h2 = (const f16*)&v2; const f16* h3 = (const f16*)&v3;
#pragma unroll
        for (int k = 0; k < 8; ++k)
            acc[k] += (float)h0[k] + (float)h1[k] + (float)h2[k] + (float)h3[k];
    }
    for (; j < s1; ++j) {
        int a = col[j];
        uint4 v = x4[(size_t)a * 16 + f8];
        const f16* hp = (const f16*)&v;
#pragma unroll
        for (int k = 0; k < 8; ++k) acc[k] += (float)hp[k];
    }
    float rs = rsqrtf(fmaxf((float)(s1 - s0), 1.f));
    const float4* b4 = (const float4*)b1;
    float4 ba = b4[f8 * 2], bb = b4[f8 * 2 + 1];
    f16x8 o;
    o[0] = (f16)(acc[0] * rs + ba.x); o[1] = (f16)(acc[1] * rs + ba.y);
    o[2] = (f16)(acc[2] * rs + ba.z); o[3] = (f16)(acc[3] * rs + ba.w);
    o[4] = (f16)(acc[4] * rs + bb.x); o[5] = (f16)(acc[5] * rs + bb.y);
    o[6] = (f16)(acc[6] * rs + bb.z); o[7] = (f16)(acc[7] * rs + bb.w);
    *(f16x8*)&y1h[(size_t)node * 128 + f8 * 8] = o;
    // BN partial sums (on fp16-rounded values, matching what gemm2 will read)
    float sv[8], qv[8];
#pragma unroll
    for (int k = 0; k < 8; ++k) { sv[k] = (float)o[k]; qv[k] = sv[k] * sv[k]; }
#pragma unroll
    for (int mask = 16; mask <= 32; mask <<= 1) {
#pragma unroll
        for (int k = 0; k < 8; ++k) {
            sv[k] += __shfl_xor(sv[k], mask);
            qv[k] += __shfl_xor(qv[k], mask);
        }
    }
    int w = tid >> 6, lane = tid & 63;
    if (lane < 16) {
#pragma unroll
        for (int k = 0; k < 8; ++k) {
            red[w * 256 + lane * 16 + k] = sv[k];
            red[w * 256 + lane * 16 + 8 + k] = qv[k];
        }
    }
    __syncthreads();
    int f8_ = tid & 15, idx = tid >> 4;   // idx 0..7 -> sum, 8..15 -> sumsq
    float tot = red[0 * 256 + f8_ * 16 + idx] + red[1 * 256 + f8_ * 16 + idx]
              + red[2 * 256 + f8_ * 16 + idx] + red[3 * 256 + f8_ * 16 + idx];
    int slot = (idx < 8) ? (f8_ * 8 + idx) : (128 + f8_ * 8 + (idx - 8));
    part[(size_t)bid * 256 + slot] = tot;
}

// ---------------- k_bnred: reduce per-block BN partials -> stats ----------------
__global__ __launch_bounds__(256) void k_bnred(const float* __restrict__ part,
                                               float* __restrict__ stats) {
    int t = threadIdx.x;
    float loc = 0.f;
    for (int b = blockIdx.x; b < NG1; b += gridDim.x)
        loc += part[(size_t)b * 256 + t];
    atomicAdd(&stats[t], loc);
}

__global__ __launch_bounds__(128) void k_bnfinal(float* __restrict__ stats,
                                                 const float* __restrict__ gamma,
                                                 const float* __restrict__ beta) {
    int f = threadIdx.x;
    float mean = stats[f] * (1.f / NN);
    float var = stats[128 + f] * (1.f / NN) - mean * mean;
    var = fmaxf(var, 0.f);
    float sc = gamma[f] * rsqrtf(var + BN_EPS);
    stats[256 + f] = sc;
    stats[384 + f] = beta[f] - mean * sc;
}

// ---------------- GEMM2 (MFMA f16): x2h = (relu(BN(y1)) .* rsqrt(degO)) @ W2 ----------------
__global__ __launch_bounds__(256) void k_gemm2(const f16* __restrict__ y1h,
                                               const f16* __restrict__ W2t,
                                               const int* __restrict__ degO,
                                               const float* __restrict__ stats,
                                               f16* __restrict__ x2h) {
    __shared__ f16 Ah[128 * 128];
    __shared__ f16 Bt[64 * 128];
    __shared__ float sc[128], sh[128], rsA[128];
    int tid = threadIdx.x;
    int row0 = blockIdx.x * 128;
    if (tid < 128) {
        sc[tid] = stats[256 + tid];
        sh[tid] = stats[384 + tid];
        int r = row0 + tid;
        float d = (r < NN) ? (float)degO[r] : 1.f;
        rsA[tid] = rsqrtf(fmaxf(d, 1.f));
    }
#pragma unroll
    for (int p = 0; p < 4; ++p) {
        int fi = p * 256 + tid;
        int r = fi >> 4, c = fi & 15;
        uint4 v = *(const uint4*)&W2t[fi * 8];
        *(uint4*)&Bt[r * 128 + ((c ^ (r & 7)) * 8)] = v;
    }
    __syncthreads();
#pragma unroll
    for (int p = 0; p < 8; ++p) {
        int fi = p * 256 + tid;
        int r = fi >> 4, c = fi & 15;
        int grow = row0 + r;
        f16x8 t;
        if (grow < NN) {
            uint4 v = *(const uint4*)&y1h[(size_t)grow * 128 + c * 8];
            const f16* hp = (const f16*)&v;
            float rs = rsA[r];
#pragma unroll
            for (int i = 0; i < 8; ++i) {
                int ch = c * 8 + i;
                float x = (float)hp[i] * sc[ch] + sh[ch];
                t[i] = (f16)(fmaxf(x, 0.f) * rs);
            }
        } else {
#pragma unroll
            for (int i = 0; i < 8; ++i) t[i] = (f16)0.f;
        }
        *(f16x8*)&Ah[r * 128 + ((c ^ (r & 7)) * 8)] = t;
    }
    __syncthreads();
    int l = tid & 63, w = tid >> 6;
    int lr = l & 15, g = l >> 4;
    int m0 = w * 32;
    f16x8 a[2][4];
#pragma unroll
    for (int m = 0; m < 2; ++m)
#pragma unroll
        for (int kk = 0; kk < 4; ++kk) {
            int row = m0 + m * 16 + lr;
            a[m][kk] = *(f16x8*)&Ah[row * 128 + (((kk * 4 + g) ^ (row & 7)) * 8)];
        }
    f32x4v acc[2][4];
#pragma unroll
    for (int m = 0; m < 2; ++m)
#pragma unroll
        for (int n = 0; n < 4; ++n) acc[m][n] = f32x4v{0.f, 0.f, 0.f, 0.f};
#pragma unroll
    for (int n = 0; n < 4; ++n) {
        int colr = n * 16 + lr;
        f16x8 b[4];
#pragma unroll
        for (int kk = 0; kk < 4; ++kk)
            b[kk] = *(f16x8*)&Bt[colr * 128 + (((kk * 4 + g) ^ (colr & 7)) * 8)];
#pragma unroll
        for (int m = 0; m < 2; ++m)
#pragma unroll
            for (int kk = 0; kk < 4; ++kk)
                acc[m][n] = __builtin_amdgcn_mfma_f32_16x16x32_f16(a[m][kk], b[kk], acc[m][n], 0, 0, 0);
    }
    __syncthreads();
#pragma unroll
    for (int m = 0; m < 2; ++m)
#pragma unroll
        for (int n = 0; n < 4; ++n)
#pragma unroll
            for (int q = 0; q < 4; ++q) {
                int row = m0 + m * 16 + g * 4 + q;
                Ah[row * 64 + n * 16 + lr] = (f16)acc[m][n][q];
            }
    __syncthreads();
#pragma unroll
    for (int p = 0; p < 4; ++p) {
        int idx = p * 64 + l;
        int r = idx >> 3, c = idx & 7;
        int row = m0 + r, grow = row0 + row;
        uint4 v = *(uint4*)&Ah[row * 64 + c * 8];
        if (grow < NN) *(uint4*)&x2h[(size_t)grow * 64 + c * 8] = v;
    }
}

// ---------------- gather2: out = (sum_j x2h[col[j]]) * rsqrt(degI) + b2 (fp32) ----------------
__global__ __launch_bounds__(256) void k_gather2(const f16* __restrict__ x2h,
                                                 const int* __restrict__ rowS,
                                                 const int* __restrict__ rowE,
                                                 const int* __restrict__ col,
                                                 const float* __restrict__ b2,
                                                 float* __restrict__ out) {
    int node = blockIdx.x * 32 + (threadIdx.x >> 3);
    int f8 = threadIdx.x & 7;
    if (node >= NN) return;
    int s0 = rowS[node], s1 = rowE[node];
    const uint4* x4 = (const uint4*)x2h;
    float acc[8] = {0.f, 0.f, 0.f, 0.f, 0.f, 0.f, 0.f, 0.f};
    int j = s0;
    for (; j + 3 < s1; j += 4) {
        uint4 v[4];
#pragma unroll
        for (int u = 0; u < 4; ++u)
            v[u] = x4[(size_t)col[j + u] * 8 + f8];
#pragma unroll
        for (int u = 0; u < 4; ++u) {
            const f16* hp = (const f16*)&v[u];
#pragma unroll
            for (int k = 0; k < 8; ++k) acc[k] += (float)hp[k];
        }
    }
    for (; j < s1; ++j) {
        uint4 v = x4[(size_t)col[j] * 8 + f8];
        const f16* hp = (const f16*)&v;
#pragma unroll
        for (int k = 0; k < 8; ++k) acc[k] += (float)hp[k];
    }
    float rs = rsqrtf(fmaxf((float)(s1 - s0), 1.f));
    const float4* b4 = (const float4*)b2;
    float4 ba = b4[f8 * 2], bb = b4[f8 * 2 + 1];
    float4 o0, o1;
    o0.x = acc[0] * rs + ba.x; o0.y = acc[1] * rs + ba.y;
    o0.z = acc[2] * rs + ba.z; o0.w = acc[3] * rs + ba.w;
    o1.x = acc[4] * rs + bb.x; o1.y = acc[5] * rs + bb.y;
    o1.z = acc[6] * rs + bb.z; o1.w = acc[7] * rs + bb.w;
    *(float4*)&out[(size_t)node * 64 + f8 * 8] = o0;
    *(float4*)&out[(size_t)node * 64 + f8 * 8 + 4] = o1;
}

extern "C" void kernel_launch(void* const* d_in, const int* in_sizes, int n_in,
                              void* d_out, int out_size, void* d_ws, size_t ws_size,
                              hipStream_t stream) {
    const float* h     = (const float*)d_in[0];
    const float* W1    = (const float*)d_in[1];
    const float* b1    = (const float*)d_in[2];
    const float* W2    = (const float*)d_in[3];
    const float* b2    = (const float*)d_in[4];
    const float* gamma = (const float*)d_in[5];
    const float* beta  = (const float*)d_in[6];
    const int*   src   = (const int*)d_in[7];
    const int*   dst   = (const int*)d_in[8];
    float* out = (float*)d_out;

    const size_t BSZ = (size_t)NB * CAP;    // 2,001,920 slots

    // workspace layout (int units from base)
    int* base = (int*)d_ws;
    float* stats = (float*)base;            // 512
    int* curD = base + 512;                 // NB
    int* curS = curD + NB;                  // NB
    int* rowS = curS + NB;                  // NN
    int* rowE = rowS + NN;                  // NN
    int* degO = rowE + NN;                  // NN
    int* col  = degO + NN;                  // BSZ ints
    unsigned* pairs = (unsigned*)(col + BSZ);               // BSZ u32
    unsigned char* srcBuck = (unsigned char*)(pairs + BSZ); // BSZ bytes
    float* part = (float*)(pairs + BSZ + (BSZ + 3) / 4);    // NG1*256 floats
    size_t o = (size_t)(col + BSZ - base) + BSZ + (BSZ + 3) / 4 + (size_t)NG1 * 256;
    o = (o + 3) & ~(size_t)3;               // 16B align
    f16* W1t = (f16*)(base + o);            // 16384 halves
    f16* W2t = W1t + 16384;                 // 8192 halves
    o += 8192 + 4096;
    f16* x1h = (f16*)(base + o);            // NN*128 halves
    o += (size_t)NN * 64;
    f16* y1h = (f16*)(base + o);            // NN*128 halves
    f16* x2h = x1h;                         // reuse (x1h dead after gather1)

    kInit<<<97, 256, 0, stream>>>(W1, W2, W1t, W2t, curD, curS, stats);

    int bgrid = (NE + EPB - 1) / EPB;       // 391
    kC<<<bgrid, 256, 0, stream>>>(src, dst, curD, curS, pairs, srcBuck);
    kDE<<<2 * NB, 256, 0, stream>>>(pairs, srcBuck, curD, curS, rowS, rowE, col, degO);

    int ggrid = (NN + 127) / 128;           // 782
    k_gemm1<<<ggrid, 256, 0, stream>>>(h, W1t, degO, x1h);
    k_gather1<<<NG1, 256, 0, stream>>>(x1h, rowS, rowE, col, b1, y1h, part);
    k_bnred<<<64, 256, 0, stream>>>(part, stats);
    k_bnfinal<<<1, 128, 0, stream>>>(stats, gamma, beta);
    k_gemm2<<<ggrid, 256, 0, stream>>>(y1h, W2t, degO, stats, x2h);
    k_gather2<<<(NN + 31) / 32, 256, 0, stream>>>(x2h, rowS, rowE, col, b2, out);
}

// Round 8
// 252.637 us; speedup vs baseline: 8.4253x; 1.0026x over previous
//
#include <hip/hip_runtime.h>

#define NN 100000
#define NE 1600000
#define NB 391          // (NN + 255) >> 8 buckets of 256 dst nodes
#define CAP 5120        // bucket capacity (mean 4092, ~16 sigma headroom)
#define EPB 8192        // edges per block in bucket pass
#define NG1 6250        // gather1 blocks = NN/16
#define NBN 64          // bn-reduce blocks
#define BN_EPS 1e-5f

typedef _Float16 f16;
typedef _Float16 f16x4 __attribute__((ext_vector_type(4)));
typedef _Float16 f16x8 __attribute__((ext_vector_type(8)));
typedef float f32x4v __attribute__((ext_vector_type(4)));

// ---------------- kInit: cursors + stats/done zero + fp16 transposed weights ----------------
__global__ __launch_bounds__(256) void kInit(const float* __restrict__ W1,
                                             const float* __restrict__ W2,
                                             f16* __restrict__ W1t,
                                             f16* __restrict__ W2t,
                                             int* __restrict__ curD,
                                             int* __restrict__ curS,
                                             float* __restrict__ stats,
                                             int* __restrict__ done) {
    int idx = blockIdx.x * 256 + threadIdx.x;
    if (idx < NB) { curD[idx] = idx * CAP; curS[idx] = idx * CAP; }
    if (idx < 512) stats[idx] = 0.f;
    if (idx == 512) done[0] = 0;
    if (idx < 16384) {
        int n = idx >> 7, k = idx & 127;
        W1t[idx] = (f16)W1[k * 128 + n];
    } else if (idx < 24576) {
        int j = idx - 16384;
        int n = j >> 7, k = j & 127;
        W2t[j] = (f16)W2[k * 64 + n];
    }
}

// ---------------- kC: bucket edges by dst>>8 (pairs) and src>>8 (srcBuck), single global read ----------------
__global__ __launch_bounds__(512) void kC(const int* __restrict__ src,
                                          const int* __restrict__ dst,
                                          int* __restrict__ curD,
                                          int* __restrict__ curS,
                                          unsigned* __restrict__ pairs,
                                          unsigned char* __restrict__ srcBuck) {
    __shared__ int sA[EPB], dA[EPB];
    __shared__ int hD[NB], hS[NB], bD_[NB], bS_[NB];
    int t = threadIdx.x;
    for (int i = t; i < NB; i += 512) { hD[i] = 0; hS[i] = 0; }
    __syncthreads();
    int e0 = blockIdx.x * EPB;
    int ne = min(EPB, NE - e0);
    // single global read: cache edges in LDS, count buckets
    for (int i = t; i < ne; i += 512) {
        int s = src[e0 + i], d = dst[e0 + i];
        sA[i] = s; dA[i] = d;
        atomicAdd(&hD[d >> 8], 1);
        atomicAdd(&hS[s >> 8], 1);
    }
    __syncthreads();
    // reserve global ranges, reset local cursors
    for (int i = t; i < NB; i += 512) {
        bD_[i] = hD[i] ? atomicAdd(&curD[i], hD[i]) : 0;
        bS_[i] = hS[i] ? atomicAdd(&curS[i], hS[i]) : 0;
        hD[i] = 0; hS[i] = 0;
    }
    __syncthreads();
    // place from LDS (packed records; defensive clamp vs capacity overflow)
    for (int i = t; i < ne; i += 512) {
        int s = sA[i], d = dA[i];
        int db = d >> 8, sb = s >> 8;
        int rD = atomicAdd(&hD[db], 1);
        int posD = bD_[db] + rD;
        int limD = (db + 1) * CAP - 1;
        if (posD > limD) posD = limD;
        pairs[posD] = ((unsigned)s << 8) | (unsigned)(d & 255);
        int rS = atomicAdd(&hS[sb], 1);
        int posS = bS_[sb] + rS;
        int limS = (sb + 1) * CAP - 1;
        if (posS > limS) posS = limS;
        srcBuck[posS] = (unsigned char)(s & 255);
    }
}

// ---------------- kDE: blocks [0,NB): per-bucket CSR; [NB,2NB): degO ----------------
__global__ __launch_bounds__(256) void kDE(const unsigned* __restrict__ pairs,
                                           const unsigned char* __restrict__ srcBuck,
                                           const int* __restrict__ curD,
                                           const int* __restrict__ curS,
                                           int* __restrict__ rowS,
                                           int* __restrict__ rowE,
                                           int* __restrict__ col,
                                           int* __restrict__ degO) {
    __shared__ unsigned bufA[CAP];                // 20 KB
    __shared__ int cnt[256], csc[256];
    int t = threadIdx.x;
    if (blockIdx.x < NB) {
        int b = blockIdx.x;
        int p0 = b * CAP;
        int n = min(curD[b] - p0, CAP);
        cnt[t] = 0;
        __syncthreads();
        for (int i = t; i < n; i += 256) {
            unsigned v = pairs[p0 + i];
            bufA[i] = v;
            atomicAdd(&cnt[v & 255u], 1);
        }
        __syncthreads();
        int vN = cnt[t];
        csc[t] = vN;
        __syncthreads();
        for (int off = 1; off < 256; off <<= 1) {
            int x = (t >= off) ? csc[t - off] : 0;
            __syncthreads();
            csc[t] += x;
            __syncthreads();
        }
        int nodeStart = csc[t] - vN;
        int node = b * 256 + t;
        if (node < NN) { rowS[node] = p0 + nodeStart; rowE[node] = p0 + nodeStart + vN; }
        cnt[t] = nodeStart;       // node scatter cursor
        __syncthreads();
        for (int i = t; i < n; i += 256) {
            unsigned v = bufA[i];
            int r = atomicAdd(&cnt[v & 255u], 1);
            col[p0 + r] = (int)(v >> 8);
        }
    } else {
        int b = blockIdx.x - NB;
        cnt[t] = 0;
        __syncthreads();
        int p0 = b * CAP;
        int p1 = min(curS[b], p0 + CAP);
        for (int p = p0 + t; p < p1; p += 256)
            atomicAdd(&cnt[srcBuck[p]], 1);
        __syncthreads();
        int node = b * 256 + t;
        if (node < NN) degO[node] = cnt[t];
    }
}

// ---------------- GEMM1 (MFMA f16): x1h = (h .* rsqrt(degO)) @ W1 ----------------
__global__ __launch_bounds__(256) void k_gemm1(const float* __restrict__ h,
                                               const f16* __restrict__ W1t,
                                               const int* __restrict__ degO,
                                               f16* __restrict__ x1h) {
    __shared__ f16 Ah[128 * 128];
    __shared__ f16 Bt[128 * 128];
    __shared__ float rsA[128];
    int tid = threadIdx.x;
    int row0 = blockIdx.x * 128;
    if (tid < 128) {
        int r = row0 + tid;
        float d = (r < NN) ? (float)degO[r] : 1.f;
        rsA[tid] = rsqrtf(fmaxf(d, 1.f));
    }
#pragma unroll
    for (int p = 0; p < 8; ++p) {
        int fi = p * 256 + tid;
        int r = fi >> 4, c = fi & 15;
        uint4 v = *(const uint4*)&W1t[fi * 8];
        *(uint4*)&Bt[r * 128 + ((c ^ (r & 7)) * 8)] = v;
    }
    __syncthreads();
#pragma unroll
    for (int p = 0; p < 16; ++p) {
        int fi = p * 256 + tid;
        int r = fi >> 5, c4 = fi & 31;
        int grow = row0 + r;
        float4 av = float4{0.f, 0.f, 0.f, 0.f};
        if (grow < NN) av = *(const float4*)&h[(size_t)grow * 128 + c4 * 4];
        float rs = rsA[r];
        f16x4 t;
        t[0] = (f16)(av.x * rs); t[1] = (f16)(av.y * rs);
        t[2] = (f16)(av.z * rs); t[3] = (f16)(av.w * rs);
        int c8 = c4 >> 1, off = (c4 & 1) * 4;
        *(f16x4*)&Ah[r * 128 + ((c8 ^ (r & 7)) * 8) + off] = t;
    }
    __syncthreads();
    int l = tid & 63, w = tid >> 6;
    int lr = l & 15, g = l >> 4;
    int m0 = w * 32;
    f16x8 a[2][4];
#pragma unroll
    for (int m = 0; m < 2; ++m)
#pragma unroll
        for (int kk = 0; kk < 4; ++kk) {
            int row = m0 + m * 16 + lr;
            a[m][kk] = *(f16x8*)&Ah[row * 128 + (((kk * 4 + g) ^ (row & 7)) * 8)];
        }
    f32x4v acc[2][8];
#pragma unroll
    for (int m = 0; m < 2; ++m)
#pragma unroll
        for (int n = 0; n < 8; ++n) acc[m][n] = f32x4v{0.f, 0.f, 0.f, 0.f};
#pragma unroll
    for (int n = 0; n < 8; ++n) {
        int colr = n * 16 + lr;
        f16x8 b[4];
#pragma unroll
        for (int kk = 0; kk < 4; ++kk)
            b[kk] = *(f16x8*)&Bt[colr * 128 + (((kk * 4 + g) ^ (colr & 7)) * 8)];
#pragma unroll
        for (int m = 0; m < 2; ++m)
#pragma unroll
            for (int kk = 0; kk < 4; ++kk)
                acc[m][n] = __builtin_amdgcn_mfma_f32_16x16x32_f16(a[m][kk], b[kk], acc[m][n], 0, 0, 0);
    }
    __syncthreads();
#pragma unroll
    for (int m = 0; m < 2; ++m)
#pragma unroll
        for (int n = 0; n < 8; ++n)
#pragma unroll
            for (int q = 0; q < 4; ++q) {
                int row = m0 + m * 16 + g * 4 + q;
                Ah[row * 128 + n * 16 + lr] = (f16)acc[m][n][q];
            }
    __syncthreads();
#pragma unroll
    for (int p = 0; p < 8; ++p) {
        int idx = p * 64 + l;
        int r = idx >> 4, c = idx & 15;
        int row = m0 + r, grow = row0 + row;
        uint4 v = *(uint4*)&Ah[row * 128 + c * 8];
        if (grow < NN) *(uint4*)&x1h[(size_t)grow * 128 + c * 8] = v;
    }
}

// ---------------- gather1: y1h = fp16( (sum_j x1h[col[j]]) * rsqrt(degI) + b1 ) + BN partials ----------------
__global__ __launch_bounds__(256) void k_gather1(const f16* __restrict__ x1h,
                                                 const int* __restrict__ rowS,
                                                 const int* __restrict__ rowE,
                                                 const int* __restrict__ col,
                                                 const float* __restrict__ b1,
                                                 f16* __restrict__ y1h,
                                                 float* __restrict__ part) {
    __shared__ float red[4 * 16 * 16];
    int tid = threadIdx.x;
    int bid = blockIdx.x;
    int node = bid * 16 + (tid >> 4);     // NN = 6250*16 exactly, no tail
    int f8 = tid & 15;
    int s0 = rowS[node], s1 = rowE[node];
    const uint4* x4 = (const uint4*)x1h;
    float acc[8] = {0.f, 0.f, 0.f, 0.f, 0.f, 0.f, 0.f, 0.f};
    int j = s0;
    for (; j + 3 < s1; j += 4) {
        int a0 = col[j], a1 = col[j + 1], a2 = col[j + 2], a3 = col[j + 3];
        uint4 v0 = x4[(size_t)a0 * 16 + f8];
        uint4 v1 = x4[(size_t)a1 * 16 + f8];
        uint4 v2 = x4[(size_t)a2 * 16 + f8];
        uint4 v3 = x4[(size_t)a3 * 16 + f8];
        const f16* h0 = (const f16*)&v0; const f16* h1 = (const f16*)&v1;
        const f16* h2 = (const f16*)&v2; const f16* h3 = (const f16*)&v3;
#pragma unroll
        for (int k = 0; k < 8; ++k)
            acc[k] += (float)h0[k] + (float)h1[k] + (float)h2[k] + (float)h3[k];
    }
    for (; j < s1; ++j) {
        int a = col[j];
        uint4 v = x4[(size_t)a * 16 + f8];
        const f16* hp = (const f16*)&v;
#pragma unroll
        for (int k = 0; k < 8; ++k) acc[k] += (float)hp[k];
    }
    float rs = rsqrtf(fmaxf((float)(s1 - s0), 1.f));
    const float4* b4 = (const float4*)b1;
    float4 ba = b4[f8 * 2], bb = b4[f8 * 2 + 1];
    f16x8 o;
    o[0] = (f16)(acc[0] * rs + ba.x); o[1] = (f16)(acc[1] * rs + ba.y);
    o[2] = (f16)(acc[2] * rs + ba.z); o[3] = (f16)(acc[3] * rs + ba.w);
    o[4] = (f16)(acc[4] * rs + bb.x); o[5] = (f16)(acc[5] * rs + bb.y);
    o[6] = (f16)(acc[6] * rs + bb.z); o[7] = (f16)(acc[7] * rs + bb.w);
    *(f16x8*)&y1h[(size_t)node * 128 + f8 * 8] = o;
    // BN partial sums (on fp16-rounded values, matching what gemm2 will read)
    float sv[8], qv[8];
#pragma unroll
    for (int k = 0; k < 8; ++k) { sv[k] = (float)o[k]; qv[k] = sv[k] * sv[k]; }
#pragma unroll
    for (int mask = 16; mask <= 32; mask <<= 1) {
#pragma unroll
        for (int k = 0; k < 8; ++k) {
            sv[k] += __shfl_xor(sv[k], mask);
            qv[k] += __shfl_xor(qv[k], mask);
        }
    }
    int w = tid >> 6, lane = tid & 63;
    if (lane < 16) {
#pragma unroll
        for (int k = 0; k < 8; ++k) {
            red[w * 256 + lane * 16 + k] = sv[k];
            red[w * 256 + lane * 16 + 8 + k] = qv[k];
        }
    }
    __syncthreads();
    int f8_ = tid & 15, idx = tid >> 4;   // idx 0..7 -> sum, 8..15 -> sumsq
    float tot = red[0 * 256 + f8_ * 16 + idx] + red[1 * 256 + f8_ * 16 + idx]
              + red[2 * 256 + f8_ * 16 + idx] + red[3 * 256 + f8_ * 16 + idx];
    int slot = (idx < 8) ? (f8_ * 8 + idx) : (128 + f8_ * 8 + (idx - 8));
    part[(size_t)bid * 256 + slot] = tot;
}

// ---------------- k_bnfin: reduce partials -> stats; last block computes scale/shift ----------------
__global__ __launch_bounds__(256) void k_bnfin(const float* __restrict__ part,
                                               float* __restrict__ stats,
                                               int* __restrict__ done,
                                               const float* __restrict__ gamma,
                                               const float* __restrict__ beta) {
    int t = threadIdx.x;
    float loc = 0.f;
    for (int b = blockIdx.x; b < NG1; b += gridDim.x)
        loc += part[(size_t)b * 256 + t];
    atomicAdd(&stats[t], loc);
    __threadfence();
    __shared__ int amLast;
    if (t == 0) amLast = (atomicAdd(done, 1) == NBN - 1) ? 1 : 0;
    __syncthreads();
    if (amLast && t < 128) {
        float s  = __hip_atomic_load(&stats[t], __ATOMIC_RELAXED, __HIP_MEMORY_SCOPE_AGENT);
        float sq = __hip_atomic_load(&stats[128 + t], __ATOMIC_RELAXED, __HIP_MEMORY_SCOPE_AGENT);
        float mean = s * (1.f / NN);
        float var = sq * (1.f / NN) - mean * mean;
        var = fmaxf(var, 0.f);
        float sc = gamma[t] * rsqrtf(var + BN_EPS);
        stats[256 + t] = sc;
        stats[384 + t] = beta[t] - mean * sc;
    }
}

// ---------------- GEMM2 (MFMA f16): x2h = (relu(BN(y1)) .* rsqrt(degO)) @ W2 ----------------
__global__ __launch_bounds__(256) void k_gemm2(const f16* __restrict__ y1h,
                                               const f16* __restrict__ W2t,
                                               const int* __restrict__ degO,
                                               const float* __restrict__ stats,
                                               f16* __restrict__ x2h) {
    __shared__ f16 Ah[128 * 128];
    __shared__ f16 Bt[64 * 128];
    __shared__ float sc[128], sh[128], rsA[128];
    int tid = threadIdx.x;
    int row0 = blockIdx.x * 128;
    if (tid < 128) {
        sc[tid] = stats[256 + tid];
        sh[tid] = stats[384 + tid];
        int r = row0 + tid;
        float d = (r < NN) ? (float)degO[r] : 1.f;
        rsA[tid] = rsqrtf(fmaxf(d, 1.f));
    }
#pragma unroll
    for (int p = 0; p < 4; ++p) {
        int fi = p * 256 + tid;
        int r = fi >> 4, c = fi & 15;
        uint4 v = *(const uint4*)&W2t[fi * 8];
        *(uint4*)&Bt[r * 128 + ((c ^ (r & 7)) * 8)] = v;
    }
    __syncthreads();
#pragma unroll
    for (int p = 0; p < 8; ++p) {
        int fi = p * 256 + tid;
        int r = fi >> 4, c = fi & 15;
        int grow = row0 + r;
        f16x8 t;
        if (grow < NN) {
            uint4 v = *(const uint4*)&y1h[(size_t)grow * 128 + c * 8];
            const f16* hp = (const f16*)&v;
            float rs = rsA[r];
#pragma unroll
            for (int i = 0; i < 8; ++i) {
                int ch = c * 8 + i;
                float x = (float)hp[i] * sc[ch] + sh[ch];
                t[i] = (f16)(fmaxf(x, 0.f) * rs);
            }
        } else {
#pragma unroll
            for (int i = 0; i < 8; ++i) t[i] = (f16)0.f;
        }
        *(f16x8*)&Ah[r * 128 + ((c ^ (r & 7)) * 8)] = t;
    }
    __syncthreads();
    int l = tid & 63, w = tid >> 6;
    int lr = l & 15, g = l >> 4;
    int m0 = w * 32;
    f16x8 a[2][4];
#pragma unroll
    for (int m = 0; m < 2; ++m)
#pragma unroll
        for (int kk = 0; kk < 4; ++kk) {
            int row = m0 + m * 16 + lr;
            a[m][kk] = *(f16x8*)&Ah[row * 128 + (((kk * 4 + g) ^ (row & 7)) * 8)];
        }
    f32x4v acc[2][4];
#pragma unroll
    for (int m = 0; m < 2; ++m)
#pragma unroll
        for (int n = 0; n < 4; ++n) acc[m][n] = f32x4v{0.f, 0.f, 0.f, 0.f};
#pragma unroll
    for (int n = 0; n < 4; ++n) {
        int colr = n * 16 + lr;
        f16x8 b[4];
#pragma unroll
        for (int kk = 0; kk < 4; ++kk)
            b[kk] = *(f16x8*)&Bt[colr * 128 + (((kk * 4 + g) ^ (colr & 7)) * 8)];
#pragma unroll
        for (int m = 0; m < 2; ++m)
#pragma unroll
            for (int kk = 0; kk < 4; ++kk)
                acc[m][n] = __builtin_amdgcn_mfma_f32_16x16x32_f16(a[m][kk], b[kk], acc[m][n], 0, 0, 0);
    }
    __syncthreads();
#pragma unroll
    for (int m = 0; m < 2; ++m)
#pragma unroll
        for (int n = 0; n < 4; ++n)
#pragma unroll
            for (int q = 0; q < 4; ++q) {
                int row = m0 + m * 16 + g * 4 + q;
                Ah[row * 64 + n * 16 + lr] = (f16)acc[m][n][q];
            }
    __syncthreads();
#pragma unroll
    for (int p = 0; p < 4; ++p) {
        int idx = p * 64 + l;
        int r = idx >> 3, c = idx & 7;
        int row = m0 + r, grow = row0 + row;
        uint4 v = *(uint4*)&Ah[row * 64 + c * 8];
        if (grow < NN) *(uint4*)&x2h[(size_t)grow * 64 + c * 8] = v;
    }
}

// ---------------- gather2: out = (sum_j x2h[col[j]]) * rsqrt(degI) + b2 (fp32) ----------------
__global__ __launch_bounds__(256) void k_gather2(const f16* __restrict__ x2h,
                                                 const int* __restrict__ rowS,
                                                 const int* __restrict__ rowE,
                                                 const int* __restrict__ col,
                                                 const float* __restrict__ b2,
                                                 float* __restrict__ out) {
    int node = blockIdx.x * 32 + (threadIdx.x >> 3);
    int f8 = threadIdx.x & 7;
    if (node >= NN) return;
    int s0 = rowS[node], s1 = rowE[node];
    const uint4* x4 = (const uint4*)x2h;
    float acc[8] = {0.f, 0.f, 0.f, 0.f, 0.f, 0.f, 0.f, 0.f};
    int j = s0;
    for (; j + 3 < s1; j += 4) {
        uint4 v[4];
#pragma unroll
        for (int u = 0; u < 4; ++u)
            v[u] = x4[(size_t)col[j + u] * 8 + f8];
#pragma unroll
        for (int u = 0; u < 4; ++u) {
            const f16* hp = (const f16*)&v[u];
#pragma unroll
            for (int k = 0; k < 8; ++k) acc[k] += (float)hp[k];
        }
    }
    for (; j < s1; ++j) {
        uint4 v = x4[(size_t)col[j] * 8 + f8];
        const f16* hp = (const f16*)&v;
#pragma unroll
        for (int k = 0; k < 8; ++k) acc[k] += (float)hp[k];
    }
    float rs = rsqrtf(fmaxf((float)(s1 - s0), 1.f));
    const float4* b4 = (const float4*)b2;
    float4 ba = b4[f8 * 2], bb = b4[f8 * 2 + 1];
    float4 o0, o1;
    o0.x = acc[0] * rs + ba.x; o0.y = acc[1] * rs + ba.y;
    o0.z = acc[2] * rs + ba.z; o0.w = acc[3] * rs + ba.w;
    o1.x = acc[4] * rs + bb.x; o1.y = acc[5] * rs + bb.y;
    o1.z = acc[6] * rs + bb.z; o1.w = acc[7] * rs + bb.w;
    *(float4*)&out[(size_t)node * 64 + f8 * 8] = o0;
    *(float4*)&out[(size_t)node * 64 + f8 * 8 + 4] = o1;
}

extern "C" void kernel_launch(void* const* d_in, const int* in_sizes, int n_in,
                              void* d_out, int out_size, void* d_ws, size_t ws_size,
                              hipStream_t stream) {
    const float* h     = (const float*)d_in[0];
    const float* W1    = (const float*)d_in[1];
    const float* b1    = (const float*)d_in[2];
    const float* W2    = (const float*)d_in[3];
    const float* b2    = (const float*)d_in[4];
    const float* gamma = (const float*)d_in[5];
    const float* beta  = (const float*)d_in[6];
    const int*   src   = (const int*)d_in[7];
    const int*   dst   = (const int*)d_in[8];
    float* out = (float*)d_out;

    const size_t BSZ = (size_t)NB * CAP;    // 2,001,920 slots

    // workspace layout (int units from base)
    int* base = (int*)d_ws;
    float* stats = (float*)base;            // 512
    int* done = base + 512;                 // 1
    int* curD = base + 513;                 // NB
    int* curS = curD + NB;                  // NB
    int* rowS = curS + NB;                  // NN
    int* rowE = rowS + NN;                  // NN
    int* degO = rowE + NN;                  // NN
    int* col  = degO + NN;                  // BSZ ints
    unsigned* pairs = (unsigned*)(col + BSZ);               // BSZ u32
    unsigned char* srcBuck = (unsigned char*)(pairs + BSZ); // BSZ bytes
    float* part = (float*)(pairs + BSZ + (BSZ + 3) / 4);    // NG1*256 floats
    size_t o = (size_t)(col + BSZ - base) + BSZ + (BSZ + 3) / 4 + (size_t)NG1 * 256;
    o = (o + 3) & ~(size_t)3;               // 16B align
    f16* W1t = (f16*)(base + o);            // 16384 halves
    f16* W2t = W1t + 16384;                 // 8192 halves
    o += 8192 + 4096;
    f16* x1h = (f16*)(base + o);            // NN*128 halves
    o += (size_t)NN * 64;
    f16* y1h = (f16*)(base + o);            // NN*128 halves
    f16* x2h = x1h;                         // reuse (x1h dead after gather1)

    kInit<<<97, 256, 0, stream>>>(W1, W2, W1t, W2t, curD, curS, stats, done);

    int bgrid = (NE + EPB - 1) / EPB;       // 196
    kC<<<bgrid, 512, 0, stream>>>(src, dst, curD, curS, pairs, srcBuck);
    kDE<<<2 * NB, 256, 0, stream>>>(pairs, srcBuck, curD, curS, rowS, rowE, col, degO);

    int ggrid = (NN + 127) / 128;           // 782
    k_gemm1<<<ggrid, 256, 0, stream>>>(h, W1t, degO, x1h);
    k_gather1<<<NG1, 256, 0, stream>>>(x1h, rowS, rowE, col, b1, y1h, part);
    k_bnfin<<<NBN, 256, 0, stream>>>(part, stats, done, gamma, beta);
    k_gemm2<<<ggrid, 256, 0, stream>>>(y1h, W2t, degO, stats, x2h);
    k_gather2<<<(NN + 31) / 32, 256, 0, stream>>>(x2h, rowS, rowE, col, b2, out);
}